// Round 5
// baseline (824.857 us; speedup 1.0000x reference)
//
#include <hip/hip_runtime.h>

#define D 128

// One edge per 64-lane wave; each lane handles 2 contiguous channels.
// edge_index dtype (int64 vs int32) is detected at runtime: under int64,
// every odd int32 word is a zero high-half (values < 50000); under genuine
// int32 the first 64 odd words being all zero has prob ~(1/50000)^64.
__global__ __launch_bounds__(256) void scatter_kernel(
    const float* __restrict__ x, const int* __restrict__ eidx,
    float* summed, float* __restrict__ counts, int E) {
    int t = blockIdx.x * 256 + threadIdx.x;
    int lane = threadIdx.x & 63;
    int probe = eidx[2 * lane + 1];                 // same 64 addrs every wave -> L2 hit
    bool is64 = (__ballot(probe != 0) == 0ULL);     // wave-uniform
    int e = t >> 6;                                 // uniform across the wave
    if (e >= E) return;
    int d = lane * 2;
    int r, c;
    if (is64) { r = eidx[2 * e];  c = eidx[2 * E + 2 * e]; }
    else      { r = eidx[e];      c = eidx[E + e]; }
    float2 v = *(const float2*)(x + (size_t)c * D + d);
    float* dst = summed + (size_t)r * D + d;
    atomicAdd(dst, v.x);
    atomicAdd(dst + 1, v.y);
    if (lane == 0) atomicAdd(counts + r, 1.0f);
}

// out[n][j] = (sum_k summed[n][k] * W[j][k]) / max(cnt[n],1) + b[j]
// IN-PLACE: summed and out share d_out. Safe: each block stages its own 32
// rows into LDS (barrier) before overwriting exactly those rows.
// 32 nodes/block, 256 threads, 4x4 outputs/thread.
// sT: [k][n] stride 36 (n<32; 16B-aligned rows, pad breaks bank pattern).
// wc: K-CHUNKED W^T slice [kk][j], kk<32, stride 132 >= 128 so the full
//     j range fits (round 3/4's bug: stride 36 with j<128 collided rows).
__global__ __launch_bounds__(256) void gemm_kernel(
    float* inout, const float* __restrict__ counts,
    const float* __restrict__ W, const float* __restrict__ bias, int N) {
    __shared__ float sT[128 * 36];   // 18 KiB   [k][n]
    __shared__ float wc[32 * 132];   // 16.5 KiB [kk][j], one 32-wide K chunk
    int t = threadIdx.x;
    int nbase = blockIdx.x * 32;

    // Stage this block's 32 rows transposed (coalesced global reads).
    #pragma unroll
    for (int i = 0; i < 16; ++i) {
        int idx = t + i * 256;
        int n = idx >> 7, k = idx & 127;
        int gn = nbase + n;
        sT[k * 36 + n] = (gn < N) ? inout[(size_t)gn * D + k] : 0.0f;
    }

    int jg = t & 31, ng = t >> 5;
    int j0 = jg * 4, n0 = ng * 4;
    float acc[4][4] = {};

    for (int kc = 0; kc < 4; ++kc) {
        __syncthreads();  // prior chunk's wc reads done (kc=0: no-op ordering)
        // Stage W chunk transposed: W[j][kc*32+kk] -> wc[kk][j].
        // idx: j = idx>>5 in [0,128), kk = idx&31; each 32-lane group reads
        // 128 contiguous bytes of a W row (coalesced).
        #pragma unroll
        for (int i = 0; i < 16; ++i) {
            int idx = t + i * 256;
            int j = idx >> 5, kk = idx & 31;
            wc[kk * 132 + j] = W[j * D + kc * 32 + kk];
        }
        __syncthreads();  // wc (and at kc=0, sT) visible

        #pragma unroll 8
        for (int kk = 0; kk < 32; ++kk) {
            int k = kc * 32 + kk;
            float4 s4 = *(const float4*)(sT + k * 36 + n0);   // broadcast across jg
            float4 w4 = *(const float4*)(wc + kk * 132 + j0);
            acc[0][0] = fmaf(s4.x, w4.x, acc[0][0]); acc[0][1] = fmaf(s4.x, w4.y, acc[0][1]);
            acc[0][2] = fmaf(s4.x, w4.z, acc[0][2]); acc[0][3] = fmaf(s4.x, w4.w, acc[0][3]);
            acc[1][0] = fmaf(s4.y, w4.x, acc[1][0]); acc[1][1] = fmaf(s4.y, w4.y, acc[1][1]);
            acc[1][2] = fmaf(s4.y, w4.z, acc[1][2]); acc[1][3] = fmaf(s4.y, w4.w, acc[1][3]);
            acc[2][0] = fmaf(s4.z, w4.x, acc[2][0]); acc[2][1] = fmaf(s4.z, w4.y, acc[2][1]);
            acc[2][2] = fmaf(s4.z, w4.z, acc[2][2]); acc[2][3] = fmaf(s4.z, w4.w, acc[2][3]);
            acc[3][0] = fmaf(s4.w, w4.x, acc[3][0]); acc[3][1] = fmaf(s4.w, w4.y, acc[3][1]);
            acc[3][2] = fmaf(s4.w, w4.z, acc[3][2]); acc[3][3] = fmaf(s4.w, w4.w, acc[3][3]);
        }
    }

    float4 b4 = *(const float4*)(bias + j0);

    #pragma unroll
    for (int i = 0; i < 4; ++i) {
        int gn = nbase + n0 + i;
        if (gn >= N) continue;
        float inv = 1.0f / fmaxf(counts[gn], 1.0f);
        float4 o;
        o.x = fmaf(acc[i][0], inv, b4.x);
        o.y = fmaf(acc[i][1], inv, b4.y);
        o.z = fmaf(acc[i][2], inv, b4.z);
        o.w = fmaf(acc[i][3], inv, b4.w);
        *(float4*)(inout + (size_t)gn * D + j0) = o;
    }
}

extern "C" void kernel_launch(void* const* d_in, const int* in_sizes, int n_in,
                              void* d_out, int out_size, void* d_ws, size_t ws_size,
                              hipStream_t stream) {
    // setup_inputs order: x, edge_index, batch_size, num_nodes, W, b
    const float* x = (const float*)d_in[0];
    const int* eidx = (const int*)d_in[1];
    const float* W = (const float*)d_in[4];
    const float* b = (const float*)d_in[5];
    float* out = (float*)d_out;

    int N = in_sizes[0] / D;   // 50000
    int E = in_sizes[1] / 2;   // 800000

    float* counts = (float*)d_ws;  // N fp32 — only ws use (200 KB)

    // out doubles as the fp32 sum accumulator; harness poisons it 0xAA.
    hipMemsetAsync(d_out, 0, (size_t)N * D * sizeof(float), stream);
    hipMemsetAsync(d_ws, 0, (size_t)N * sizeof(float), stream);

    int sblocks = (E * 64 + 255) / 256;  // one wave per edge
    scatter_kernel<<<sblocks, 256, 0, stream>>>(x, eidx, out, counts, E);

    int gblocks = (N + 31) / 32;
    gemm_kernel<<<gblocks, 256, 0, stream>>>(out, counts, W, b, N);
}

// Round 6
// 274.873 us; speedup vs baseline: 3.0009x; 3.0009x over previous
//
#include <hip/hip_runtime.h>

#define D 128
#define SCAN_CHUNK 1024

// ---- edge-index dtype probe (int64 vs int32), wave-uniform, ~free ----
__device__ __forceinline__ bool eidx_is64(const int* eidx, int lane) {
    int probe = eidx[2 * lane + 1];              // L2-hit after first wave
    return __ballot(probe != 0) == 0ULL;         // int64 high halves all zero
}

// ---- CSR build ----
__global__ __launch_bounds__(256) void hist_kernel(
    const int* __restrict__ eidx, int* __restrict__ cnt, int E) {
    int lane = threadIdx.x & 63;
    bool is64 = eidx_is64(eidx, lane);
    int e = blockIdx.x * 256 + threadIdx.x;
    if (e >= E) return;
    int r = is64 ? eidx[2 * e] : eidx[e];
    atomicAdd(&cnt[r], 1);
}

// Exclusive scan, stage 1: each block scans 1024 counts, emits partial
// prefixes (exclusive within block) + block total.
__global__ __launch_bounds__(256) void scan1_kernel(
    const int* __restrict__ cnt, int* __restrict__ partial,
    int* __restrict__ bsum, int N) {
    __shared__ int s[256];
    int t = threadIdx.x;
    int base = blockIdx.x * SCAN_CHUNK + t * 4;
    int v[4], sum = 0;
    #pragma unroll
    for (int i = 0; i < 4; ++i) {
        v[i] = (base + i < N) ? cnt[base + i] : 0;
        sum += v[i];
    }
    s[t] = sum;
    __syncthreads();
    #pragma unroll
    for (int off = 1; off < 256; off <<= 1) {
        int x = (t >= off) ? s[t - off] : 0;
        __syncthreads();
        s[t] += x;
        __syncthreads();
    }
    if (t == 255) bsum[blockIdx.x] = s[255];
    int run = s[t] - sum;  // exclusive prefix of this thread
    #pragma unroll
    for (int i = 0; i < 4; ++i) {
        if (base + i < N) partial[base + i] = run;
        run += v[i];
    }
}

// Stage 2: exclusive scan of the <=256 block totals.
__global__ __launch_bounds__(256) void scan2_kernel(
    const int* __restrict__ bsum, int* __restrict__ boff, int NB) {
    __shared__ int s[256];
    int t = threadIdx.x;
    int v = (t < NB) ? bsum[t] : 0;
    s[t] = v;
    __syncthreads();
    #pragma unroll
    for (int off = 1; off < 256; off <<= 1) {
        int x = (t >= off) ? s[t - off] : 0;
        __syncthreads();
        s[t] += x;
        __syncthreads();
    }
    if (t < NB) boff[t] = s[t] - v;
}

__global__ __launch_bounds__(256) void fill_kernel(
    const int* __restrict__ eidx, const int* __restrict__ partial,
    const int* __restrict__ boff, int* __restrict__ cursor,
    int* __restrict__ elist, int E) {
    int lane = threadIdx.x & 63;
    bool is64 = eidx_is64(eidx, lane);
    int e = blockIdx.x * 256 + threadIdx.x;
    if (e >= E) return;
    int r, c;
    if (is64) { r = eidx[2 * e]; c = eidx[2 * E + 2 * e]; }
    else      { r = eidx[e];     c = eidx[E + e]; }
    int pos = atomicAdd(&cursor[r], 1);
    elist[partial[r] + boff[r >> 10] + pos] = c;
}

// One wave per output row: gather x[col] rows (coalesced 512 B/row),
// register-accumulate, apply mean, single write. Zero fp32 atomics.
__global__ __launch_bounds__(256) void gather_kernel(
    const float* __restrict__ x, const int* __restrict__ elist,
    const int* __restrict__ cnt, const int* __restrict__ partial,
    const int* __restrict__ boff, float* __restrict__ out, int N) {
    int g = blockIdx.x * 256 + threadIdx.x;
    int r = g >> 6;
    if (r >= N) return;
    int lane = g & 63;
    int n = cnt[r];                          // wave-uniform
    int beg = partial[r] + boff[r >> 10];    // wave-uniform
    int end = beg + n;
    float ax = 0.f, ay = 0.f;
    int i = beg;
    for (; i + 2 <= end; i += 2) {           // unroll-2 for memory ILP
        int c0 = elist[i], c1 = elist[i + 1];
        float2 v0 = *(const float2*)(x + (size_t)c0 * D + 2 * lane);
        float2 v1 = *(const float2*)(x + (size_t)c1 * D + 2 * lane);
        ax += v0.x + v1.x;
        ay += v0.y + v1.y;
    }
    if (i < end) {
        int c0 = elist[i];
        float2 v0 = *(const float2*)(x + (size_t)c0 * D + 2 * lane);
        ax += v0.x; ay += v0.y;
    }
    float inv = (n > 0) ? 1.0f / (float)n : 0.0f;
    float2 o = { ax * inv, ay * inv };
    *(float2*)(out + (size_t)r * D + 2 * lane) = o;
}

// ---- fallback path (ws too small): round-5 proven atomic scatter ----
__global__ __launch_bounds__(256) void scatter_kernel(
    const float* __restrict__ x, const int* __restrict__ eidx,
    float* summed, float* __restrict__ counts, int E) {
    int t = blockIdx.x * 256 + threadIdx.x;
    int lane = threadIdx.x & 63;
    bool is64 = eidx_is64(eidx, lane);
    int e = t >> 6;
    if (e >= E) return;
    int d = lane * 2;
    int r, c;
    if (is64) { r = eidx[2 * e]; c = eidx[2 * E + 2 * e]; }
    else      { r = eidx[e];     c = eidx[E + e]; }
    float2 v = *(const float2*)(x + (size_t)c * D + d);
    float* dst = summed + (size_t)r * D + d;
    atomicAdd(dst, v.x);
    atomicAdd(dst + 1, v.y);
    if (lane == 0) atomicAdd(counts + r, 1.0f);
}

__global__ __launch_bounds__(256) void divide_kernel(
    float* __restrict__ sums, const float* __restrict__ counts, int N) {
    int g = blockIdx.x * 256 + threadIdx.x;
    int r = g >> 6, lane = g & 63;
    if (r >= N) return;
    float inv = 1.0f / fmaxf(counts[r], 1.0f);
    float2* p = (float2*)(sums + (size_t)r * D + 2 * lane);
    float2 v = *p;
    v.x *= inv; v.y *= inv;
    *p = v;
}

// out[n][j] = sum_k mean[n][k] * W[j][k] + b[j]   (IN-PLACE on d_out)
// 32 rows/block, 256 threads, 4x4 outputs/thread; K chunked by 32 so the
// full-width W^T slice (stride 132 >= 128) fits in LDS.
__global__ __launch_bounds__(256) void gemm_kernel(
    float* inout, const float* __restrict__ W,
    const float* __restrict__ bias, int N) {
    __shared__ float sT[128 * 36];   // 18 KiB   [k][n], n<32
    __shared__ float wc[32 * 132];   // 16.5 KiB [kk][j], one 32-wide K chunk
    int t = threadIdx.x;
    int nbase = blockIdx.x * 32;

    #pragma unroll
    for (int i = 0; i < 16; ++i) {
        int idx = t + i * 256;
        int n = idx >> 7, k = idx & 127;
        int gn = nbase + n;
        sT[k * 36 + n] = (gn < N) ? inout[(size_t)gn * D + k] : 0.0f;
    }

    int jg = t & 31, ng = t >> 5;
    int j0 = jg * 4, n0 = ng * 4;
    float acc[4][4] = {};

    for (int kc = 0; kc < 4; ++kc) {
        __syncthreads();
        #pragma unroll
        for (int i = 0; i < 16; ++i) {
            int idx = t + i * 256;
            int j = idx >> 5, kk = idx & 31;
            wc[kk * 132 + j] = W[j * D + kc * 32 + kk];
        }
        __syncthreads();

        #pragma unroll 8
        for (int kk = 0; kk < 32; ++kk) {
            int k = kc * 32 + kk;
            float4 s4 = *(const float4*)(sT + k * 36 + n0);
            float4 w4 = *(const float4*)(wc + kk * 132 + j0);
            acc[0][0] = fmaf(s4.x, w4.x, acc[0][0]); acc[0][1] = fmaf(s4.x, w4.y, acc[0][1]);
            acc[0][2] = fmaf(s4.x, w4.z, acc[0][2]); acc[0][3] = fmaf(s4.x, w4.w, acc[0][3]);
            acc[1][0] = fmaf(s4.y, w4.x, acc[1][0]); acc[1][1] = fmaf(s4.y, w4.y, acc[1][1]);
            acc[1][2] = fmaf(s4.y, w4.z, acc[1][2]); acc[1][3] = fmaf(s4.y, w4.w, acc[1][3]);
            acc[2][0] = fmaf(s4.z, w4.x, acc[2][0]); acc[2][1] = fmaf(s4.z, w4.y, acc[2][1]);
            acc[2][2] = fmaf(s4.z, w4.z, acc[2][2]); acc[2][3] = fmaf(s4.z, w4.w, acc[2][3]);
            acc[3][0] = fmaf(s4.w, w4.x, acc[3][0]); acc[3][1] = fmaf(s4.w, w4.y, acc[3][1]);
            acc[3][2] = fmaf(s4.w, w4.z, acc[3][2]); acc[3][3] = fmaf(s4.w, w4.w, acc[3][3]);
        }
    }

    float4 b4 = *(const float4*)(bias + j0);
    #pragma unroll
    for (int i = 0; i < 4; ++i) {
        int gn = nbase + n0 + i;
        if (gn >= N) continue;
        float4 o;
        o.x = acc[i][0] + b4.x;
        o.y = acc[i][1] + b4.y;
        o.z = acc[i][2] + b4.z;
        o.w = acc[i][3] + b4.w;
        *(float4*)(inout + (size_t)gn * D + j0) = o;
    }
}

extern "C" void kernel_launch(void* const* d_in, const int* in_sizes, int n_in,
                              void* d_out, int out_size, void* d_ws, size_t ws_size,
                              hipStream_t stream) {
    // setup_inputs order: x, edge_index, batch_size, num_nodes, W, b
    const float* x = (const float*)d_in[0];
    const int* eidx = (const int*)d_in[1];
    const float* W = (const float*)d_in[4];
    const float* b = (const float*)d_in[5];
    float* out = (float*)d_out;

    int N = in_sizes[0] / D;   // 50000
    int E = in_sizes[1] / 2;   // 800000
    int NB = (N + SCAN_CHUNK - 1) / SCAN_CHUNK;  // 49

    // ws layout (ints), 256B-aligned segments; cnt+cursor first (one memset).
    size_t o0 = 0;
    size_t o_cnt = o0;                    o0 += ((size_t)N * 4 + 255) & ~255ULL;
    size_t o_cur = o0;                    o0 += ((size_t)N * 4 + 255) & ~255ULL;
    size_t o_par = o0;                    o0 += ((size_t)N * 4 + 255) & ~255ULL;
    size_t o_bs  = o0;                    o0 += 1024;
    size_t o_bo  = o0;                    o0 += 1024;
    size_t o_el  = o0;                    o0 += (size_t)E * 4;
    bool csr_ok = (ws_size >= o0);

    if (csr_ok) {
        char* ws = (char*)d_ws;
        int* cnt    = (int*)(ws + o_cnt);
        int* cursor = (int*)(ws + o_cur);
        int* partial= (int*)(ws + o_par);
        int* bsum   = (int*)(ws + o_bs);
        int* boff   = (int*)(ws + o_bo);
        int* elist  = (int*)(ws + o_el);

        hipMemsetAsync(ws, 0, o_par, stream);  // zero cnt + cursor

        int eb = (E + 255) / 256;
        hist_kernel<<<eb, 256, 0, stream>>>(eidx, cnt, E);
        scan1_kernel<<<NB, 256, 0, stream>>>(cnt, partial, bsum, N);
        scan2_kernel<<<1, 256, 0, stream>>>(bsum, boff, NB);
        fill_kernel<<<eb, 256, 0, stream>>>(eidx, partial, boff, cursor, elist, E);

        int gb = (N * 64 + 255) / 256;
        gather_kernel<<<gb, 256, 0, stream>>>(x, elist, cnt, partial, boff, out, N);
    } else {
        // fallback: proven atomic-scatter path (needs only N floats of ws)
        float* counts = (float*)d_ws;
        hipMemsetAsync(d_out, 0, (size_t)N * D * sizeof(float), stream);
        hipMemsetAsync(d_ws, 0, (size_t)N * sizeof(float), stream);
        int sb = (E * 64 + 255) / 256;
        scatter_kernel<<<sb, 256, 0, stream>>>(x, eidx, out, counts, E);
        int db = (N * 64 + 255) / 256;
        divide_kernel<<<db, 256, 0, stream>>>(out, counts, N);
    }

    int gemm_b = (N + 31) / 32;
    gemm_kernel<<<gemm_b, 256, 0, stream>>>(out, W, b, N);
}

// Round 7
// 229.521 us; speedup vs baseline: 3.5938x; 1.1976x over previous
//
#include <hip/hip_runtime.h>

#define D 128
#define SCAN_CHUNK 1024

// ---- edge-index dtype probe (int64 vs int32), wave-uniform, ~free ----
__device__ __forceinline__ bool eidx_is64(const int* eidx, int lane) {
    int probe = eidx[2 * lane + 1];              // L2-hit after first wave
    return __ballot(probe != 0) == 0ULL;         // int64 high halves all zero
}

// ---- CSR build ----
// Histogram + per-edge position in one pass: pos[e] = old count of row r.
__global__ __launch_bounds__(256) void hist_kernel(
    const int* __restrict__ eidx, int* __restrict__ cnt,
    int* __restrict__ pos, int E) {
    int lane = threadIdx.x & 63;
    bool is64 = eidx_is64(eidx, lane);
    int e = blockIdx.x * 256 + threadIdx.x;
    if (e >= E) return;
    int r = is64 ? eidx[2 * e] : eidx[e];
    pos[e] = atomicAdd(&cnt[r], 1);
}

// Exclusive scan, stage 1: each block scans 1024 counts, emits exclusive
// in-block prefixes + block total.
__global__ __launch_bounds__(256) void scan1_kernel(
    const int* __restrict__ cnt, int* __restrict__ partial,
    int* __restrict__ bsum, int N) {
    __shared__ int s[256];
    int t = threadIdx.x;
    int base = blockIdx.x * SCAN_CHUNK + t * 4;
    int v[4], sum = 0;
    #pragma unroll
    for (int i = 0; i < 4; ++i) {
        v[i] = (base + i < N) ? cnt[base + i] : 0;
        sum += v[i];
    }
    s[t] = sum;
    __syncthreads();
    #pragma unroll
    for (int off = 1; off < 256; off <<= 1) {
        int x = (t >= off) ? s[t - off] : 0;
        __syncthreads();
        s[t] += x;
        __syncthreads();
    }
    if (t == 255) bsum[blockIdx.x] = s[255];
    int run = s[t] - sum;  // exclusive prefix of this thread
    #pragma unroll
    for (int i = 0; i < 4; ++i) {
        if (base + i < N) partial[base + i] = run;
        run += v[i];
    }
}

// Stage 2: exclusive scan of the <=256 block totals.
__global__ __launch_bounds__(256) void scan2_kernel(
    const int* __restrict__ bsum, int* __restrict__ boff, int NB) {
    __shared__ int s[256];
    int t = threadIdx.x;
    int v = (t < NB) ? bsum[t] : 0;
    s[t] = v;
    __syncthreads();
    #pragma unroll
    for (int off = 1; off < 256; off <<= 1) {
        int x = (t >= off) ? s[t - off] : 0;
        __syncthreads();
        s[t] += x;
        __syncthreads();
    }
    if (t < NB) boff[t] = s[t] - v;
}

// Atomic-free fill: slot known from hist's pos[e].
__global__ __launch_bounds__(256) void fill_kernel(
    const int* __restrict__ eidx, const int* __restrict__ partial,
    const int* __restrict__ boff, const int* __restrict__ pos,
    int* __restrict__ elist, int E) {
    int lane = threadIdx.x & 63;
    bool is64 = eidx_is64(eidx, lane);
    int e = blockIdx.x * 256 + threadIdx.x;
    if (e >= E) return;
    int r, c;
    if (is64) { r = eidx[2 * e]; c = eidx[2 * E + 2 * e]; }
    else      { r = eidx[e];     c = eidx[E + e]; }
    elist[partial[r] + boff[r >> 10] + pos[e]] = c;
}

// ---- FUSED mean-aggregate + linear ----
// Block = 256 threads, 32 output rows. Phase 1: each wave gathers 8 rows
// (x[col] rows as coalesced 512 B loads, 4-edge unroll for memory ILP),
// writing the MEAN transposed into LDS sT[k][n]. Phase 2: K-chunked
// register-tile GEMM (4x4 outputs/thread) vs W^T slices, bias epilogue,
// single coalesced write to out. No intermediate global buffer.
__global__ __launch_bounds__(256, 6) void fused_kernel(
    const float* __restrict__ x, const int* __restrict__ elist,
    const int* __restrict__ cnt, const int* __restrict__ partial,
    const int* __restrict__ boff, const float* __restrict__ W,
    const float* __restrict__ bias, float* __restrict__ out, int N) {
    __shared__ float sT[128 * 36];   // 18 KiB    [k][n], n<32 (mean, transposed)
    __shared__ float wc[16 * 132];   // 8.25 KiB  [kk][j], one 16-wide K chunk
    int t = threadIdx.x;
    int lane = t & 63, wave = t >> 6;
    int nbase = blockIdx.x * 32;

    // ---- Phase 1: gather means into sT ----
    #pragma unroll
    for (int i = 0; i < 8; ++i) {
        int n = wave * 8 + i;
        int gn = nbase + n;
        float ax = 0.f, ay = 0.f, inv = 0.f;
        if (gn < N) {
            int nr = cnt[gn];                        // wave-uniform
            int beg = partial[gn] + boff[gn >> 10];  // wave-uniform
            int end = beg + nr;
            int ii = beg;
            for (; ii + 4 <= end; ii += 4) {         // 4 rows in flight
                int c0 = elist[ii], c1 = elist[ii + 1];
                int c2 = elist[ii + 2], c3 = elist[ii + 3];
                float2 v0 = *(const float2*)(x + (size_t)c0 * D + 2 * lane);
                float2 v1 = *(const float2*)(x + (size_t)c1 * D + 2 * lane);
                float2 v2 = *(const float2*)(x + (size_t)c2 * D + 2 * lane);
                float2 v3 = *(const float2*)(x + (size_t)c3 * D + 2 * lane);
                ax += (v0.x + v1.x) + (v2.x + v3.x);
                ay += (v0.y + v1.y) + (v2.y + v3.y);
            }
            for (; ii < end; ++ii) {
                int c0 = elist[ii];
                float2 v0 = *(const float2*)(x + (size_t)c0 * D + 2 * lane);
                ax += v0.x; ay += v0.y;
            }
            inv = (nr > 0) ? 1.0f / (float)nr : 0.0f;
        }
        sT[(2 * lane) * 36 + n] = ax * inv;
        sT[(2 * lane + 1) * 36 + n] = ay * inv;
    }

    // ---- Phase 2: out[n][j] = sum_k sT[k][n] * W[j][k] + b[j] ----
    int jg = t & 31, ng = t >> 5;
    int j0 = jg * 4, n0 = ng * 4;
    float acc[4][4] = {};

    for (int kc = 0; kc < 8; ++kc) {
        __syncthreads();  // kc=0: sT complete; kc>0: prior wc reads done
        // Stage W chunk transposed: W[j][kc*16+kk] -> wc[kk][j].
        #pragma unroll
        for (int i = 0; i < 8; ++i) {
            int idx = t + i * 256;
            int j = idx >> 4, kk = idx & 15;
            wc[kk * 132 + j] = W[j * D + kc * 16 + kk];
        }
        __syncthreads();

        #pragma unroll
        for (int kk = 0; kk < 16; ++kk) {
            int k = kc * 16 + kk;
            float4 s4 = *(const float4*)(sT + k * 36 + n0);
            float4 w4 = *(const float4*)(wc + kk * 132 + j0);
            acc[0][0] = fmaf(s4.x, w4.x, acc[0][0]); acc[0][1] = fmaf(s4.x, w4.y, acc[0][1]);
            acc[0][2] = fmaf(s4.x, w4.z, acc[0][2]); acc[0][3] = fmaf(s4.x, w4.w, acc[0][3]);
            acc[1][0] = fmaf(s4.y, w4.x, acc[1][0]); acc[1][1] = fmaf(s4.y, w4.y, acc[1][1]);
            acc[1][2] = fmaf(s4.y, w4.z, acc[1][2]); acc[1][3] = fmaf(s4.y, w4.w, acc[1][3]);
            acc[2][0] = fmaf(s4.z, w4.x, acc[2][0]); acc[2][1] = fmaf(s4.z, w4.y, acc[2][1]);
            acc[2][2] = fmaf(s4.z, w4.z, acc[2][2]); acc[2][3] = fmaf(s4.z, w4.w, acc[2][3]);
            acc[3][0] = fmaf(s4.w, w4.x, acc[3][0]); acc[3][1] = fmaf(s4.w, w4.y, acc[3][1]);
            acc[3][2] = fmaf(s4.w, w4.z, acc[3][2]); acc[3][3] = fmaf(s4.w, w4.w, acc[3][3]);
        }
    }

    float4 b4 = *(const float4*)(bias + j0);
    #pragma unroll
    for (int i = 0; i < 4; ++i) {
        int gn = nbase + n0 + i;
        if (gn >= N) continue;
        float4 o;
        o.x = acc[i][0] + b4.x;
        o.y = acc[i][1] + b4.y;
        o.z = acc[i][2] + b4.z;
        o.w = acc[i][3] + b4.w;
        *(float4*)(out + (size_t)gn * D + j0) = o;
    }
}

// ---- fallback path (ws too small): round-5 proven atomic scatter ----
__global__ __launch_bounds__(256) void scatter_kernel(
    const float* __restrict__ x, const int* __restrict__ eidx,
    float* summed, float* __restrict__ counts, int E) {
    int t = blockIdx.x * 256 + threadIdx.x;
    int lane = threadIdx.x & 63;
    bool is64 = eidx_is64(eidx, lane);
    int e = t >> 6;
    if (e >= E) return;
    int d = lane * 2;
    int r, c;
    if (is64) { r = eidx[2 * e]; c = eidx[2 * E + 2 * e]; }
    else      { r = eidx[e];     c = eidx[E + e]; }
    float2 v = *(const float2*)(x + (size_t)c * D + d);
    float* dst = summed + (size_t)r * D + d;
    atomicAdd(dst, v.x);
    atomicAdd(dst + 1, v.y);
    if (lane == 0) atomicAdd(counts + r, 1.0f);
}

__global__ __launch_bounds__(256) void divide_kernel(
    float* __restrict__ sums, const float* __restrict__ counts, int N) {
    int g = blockIdx.x * 256 + threadIdx.x;
    int r = g >> 6, lane = g & 63;
    if (r >= N) return;
    float inv = 1.0f / fmaxf(counts[r], 1.0f);
    float2* p = (float2*)(sums + (size_t)r * D + 2 * lane);
    float2 v = *p;
    v.x *= inv; v.y *= inv;
    *p = v;
}

// In-place GEMM for the fallback path (round-5 proven).
__global__ __launch_bounds__(256) void gemm_kernel(
    float* inout, const float* __restrict__ W,
    const float* __restrict__ bias, int N) {
    __shared__ float sT[128 * 36];
    __shared__ float wc[32 * 132];
    int t = threadIdx.x;
    int nbase = blockIdx.x * 32;

    #pragma unroll
    for (int i = 0; i < 16; ++i) {
        int idx = t + i * 256;
        int n = idx >> 7, k = idx & 127;
        int gn = nbase + n;
        sT[k * 36 + n] = (gn < N) ? inout[(size_t)gn * D + k] : 0.0f;
    }

    int jg = t & 31, ng = t >> 5;
    int j0 = jg * 4, n0 = ng * 4;
    float acc[4][4] = {};

    for (int kc = 0; kc < 4; ++kc) {
        __syncthreads();
        #pragma unroll
        for (int i = 0; i < 16; ++i) {
            int idx = t + i * 256;
            int j = idx >> 5, kk = idx & 31;
            wc[kk * 132 + j] = W[j * D + kc * 32 + kk];
        }
        __syncthreads();
        #pragma unroll 8
        for (int kk = 0; kk < 32; ++kk) {
            int k = kc * 32 + kk;
            float4 s4 = *(const float4*)(sT + k * 36 + n0);
            float4 w4 = *(const float4*)(wc + kk * 132 + j0);
            acc[0][0] = fmaf(s4.x, w4.x, acc[0][0]); acc[0][1] = fmaf(s4.x, w4.y, acc[0][1]);
            acc[0][2] = fmaf(s4.x, w4.z, acc[0][2]); acc[0][3] = fmaf(s4.x, w4.w, acc[0][3]);
            acc[1][0] = fmaf(s4.y, w4.x, acc[1][0]); acc[1][1] = fmaf(s4.y, w4.y, acc[1][1]);
            acc[1][2] = fmaf(s4.y, w4.z, acc[1][2]); acc[1][3] = fmaf(s4.y, w4.w, acc[1][3]);
            acc[2][0] = fmaf(s4.z, w4.x, acc[2][0]); acc[2][1] = fmaf(s4.z, w4.y, acc[2][1]);
            acc[2][2] = fmaf(s4.z, w4.z, acc[2][2]); acc[2][3] = fmaf(s4.z, w4.w, acc[2][3]);
            acc[3][0] = fmaf(s4.w, w4.x, acc[3][0]); acc[3][1] = fmaf(s4.w, w4.y, acc[3][1]);
            acc[3][2] = fmaf(s4.w, w4.z, acc[3][2]); acc[3][3] = fmaf(s4.w, w4.w, acc[3][3]);
        }
    }

    float4 b4 = *(const float4*)(bias + j0);
    #pragma unroll
    for (int i = 0; i < 4; ++i) {
        int gn = nbase + n0 + i;
        if (gn >= N) continue;
        float4 o;
        o.x = acc[i][0] + b4.x;
        o.y = acc[i][1] + b4.y;
        o.z = acc[i][2] + b4.z;
        o.w = acc[i][3] + b4.w;
        *(float4*)(inout + (size_t)gn * D + j0) = o;
    }
}

extern "C" void kernel_launch(void* const* d_in, const int* in_sizes, int n_in,
                              void* d_out, int out_size, void* d_ws, size_t ws_size,
                              hipStream_t stream) {
    // setup_inputs order: x, edge_index, batch_size, num_nodes, W, b
    const float* x = (const float*)d_in[0];
    const int* eidx = (const int*)d_in[1];
    const float* W = (const float*)d_in[4];
    const float* b = (const float*)d_in[5];
    float* out = (float*)d_out;

    int N = in_sizes[0] / D;   // 50000
    int E = in_sizes[1] / 2;   // 800000
    int NB = (N + SCAN_CHUNK - 1) / SCAN_CHUNK;  // 49

    // ws layout, 256B-aligned segments.
    size_t o0 = 0;
    size_t o_cnt = o0;   o0 += ((size_t)N * 4 + 255) & ~255ULL;
    size_t o_par = o0;   o0 += ((size_t)N * 4 + 255) & ~255ULL;
    size_t o_bs  = o0;   o0 += 1024;
    size_t o_bo  = o0;   o0 += 1024;
    size_t o_pos = o0;   o0 += (size_t)E * 4;
    size_t o_el  = o0;   o0 += (size_t)E * 4;
    bool csr_ok = (ws_size >= o0);

    if (csr_ok) {
        char* ws = (char*)d_ws;
        int* cnt     = (int*)(ws + o_cnt);
        int* partial = (int*)(ws + o_par);
        int* bsum    = (int*)(ws + o_bs);
        int* boff    = (int*)(ws + o_bo);
        int* pos     = (int*)(ws + o_pos);
        int* elist   = (int*)(ws + o_el);

        hipMemsetAsync(cnt, 0, (size_t)N * 4, stream);  // only cnt needs zeros

        int eb = (E + 255) / 256;
        hist_kernel<<<eb, 256, 0, stream>>>(eidx, cnt, pos, E);
        scan1_kernel<<<NB, 256, 0, stream>>>(cnt, partial, bsum, N);
        scan2_kernel<<<1, 256, 0, stream>>>(bsum, boff, NB);
        fill_kernel<<<eb, 256, 0, stream>>>(eidx, partial, boff, pos, elist, E);

        int fb = (N + 31) / 32;
        fused_kernel<<<fb, 256, 0, stream>>>(x, elist, cnt, partial, boff,
                                             W, b, out, N);
    } else {
        // fallback: proven atomic-scatter path (needs only N floats of ws)
        float* counts = (float*)d_ws;
        hipMemsetAsync(d_out, 0, (size_t)N * D * sizeof(float), stream);
        hipMemsetAsync(d_ws, 0, (size_t)N * sizeof(float), stream);
        int sb = (E * 64 + 255) / 256;
        scatter_kernel<<<sb, 256, 0, stream>>>(x, eidx, out, counts, E);
        int db = (N * 64 + 255) / 256;
        divide_kernel<<<db, 256, 0, stream>>>(out, counts, N);
        int gb = (N + 31) / 32;
        gemm_kernel<<<gb, 256, 0, stream>>>(out, W, b, N);
    }
}